// Round 4
// baseline (137.987 us; speedup 1.0000x reference)
//
#include <hip/hip_runtime.h>
#include <hip/hip_bf16.h>

typedef __bf16 bf16x8 __attribute__((ext_vector_type(8)));
typedef float floatx4 __attribute__((ext_vector_type(4)));
typedef unsigned short u16;
typedef unsigned int u32;

#define HW 196      // 14*14
#define NB 8
#define NC 128
#define CL 480      // xfe row stride (u16); reads bounded by 430 < 480
#define WROW 12544  // u32 per (b,a1) row of W (= 25088 bf16 = 128c * 196p)

// ws offsets (bytes)
#define OFF_XFRSW 0            // 8 * 3584 uint4 = 458752 B  (A in MFMA-frag order)
#define OFF_XFE   458752       // 8*128*8*480*2 = 7864320 B  (8 shift-copies / row)
#define OFF_W     8323072      // 12845056 B
#define OFF_SUMS  21168128

// ---- Stage 1: 1x1 conv + ReLU + 3x3 Gaussian blur; emits:
//  xfr_sw[b][kb7][at8][quad4][m16][j8]  = reversed row (A-operand, frag order)
//  xfe[b][c][S8][CL]                    = row_c[(m+S) mod 196] (B shift table)
// grid (8 b, 16 og-of-8-rows), 512 threads = (K-half, pixel).
__global__ __launch_bounds__(512) void k_stage1(const float* __restrict__ x,
                                                const float* __restrict__ wc,
                                                uint4* __restrict__ xfr_sw,
                                                u16* __restrict__ xfe) {
  const int b   = blockIdx.x;
  const int og  = blockIdx.y;      // rows og*8 .. og*8+7
  const int t   = threadIdx.x;
  const int pix = t & 255;
  const int half = t >> 8;
  const float* xb = x + ((size_t)(b * 512 + half * 256)) * 256 + pix;
  const float* w0 = wc + og * 8 * 512 + half * 256;   // wave-uniform -> s_load

  float a[8] = {0.f, 0.f, 0.f, 0.f, 0.f, 0.f, 0.f, 0.f};
#pragma unroll 8
  for (int i = 0; i < 256; ++i) {
    float xv = xb[(size_t)i * 256];
#pragma unroll
    for (int oo = 0; oo < 8; ++oo) a[oo] = fmaf(xv, w0[oo * 512 + i], a[oo]);
  }

  __shared__ float ybuf[8][512];
#pragma unroll
  for (int oo = 0; oo < 8; ++oo) ybuf[oo][t] = a[oo];
  __syncthreads();
  if (t < 256) {
#pragma unroll
    for (int oo = 0; oo < 8; ++oo)
      ybuf[oo][t] = fmaxf(ybuf[oo][t] + ybuf[oo][256 + t], 0.f);
  }
  __syncthreads();

  const float GC = 0.63661977236758138f;   // gaussian var 0.25
  const float GE = GC * 0.13533528323661270f;
  const float GD = GC * 0.018315638888734179f;

  __shared__ u16 ydup[8][592];   // blurred row, bf16, replicated 3x (idx 0..587)
  if (t < HW) {
    const int h = t / 14, w2 = t - h * 14;
#pragma unroll
    for (int oo = 0; oo < 8; ++oo) {
      const float* yb = &ybuf[oo][h * 16 + w2];
      float v = GD * (yb[0] + yb[2] + yb[32] + yb[34])
              + GE * (yb[1] + yb[16] + yb[18] + yb[33])
              + GC * yb[17];
      union { __hip_bfloat16 h2; u16 u; } cv; cv.h2 = __float2bfloat16(v);
      ydup[oo][t] = cv.u; ydup[oo][t + 196] = cv.u; ydup[oo][t + 392] = cv.u;
    }
  }
  __syncthreads();

  // xfr_sw: per row 28 uint4 (g = k>>3), reversed: Arev[k] = y[(196-k)%196], 0 for k>=196
  if (t < 224) {
    const int oo = t / 28;
    const int g  = t - oo * 28;          // 0..27 = kb*4 + quad
    const int kb = g >> 2, quad = g & 3;
    const int c  = og * 8 + oo;
    const int at = c >> 4, m = c & 15;
    union { u16 u[8]; uint4 v; } pk;
#pragma unroll
    for (int j = 0; j < 8; ++j) {
      const int k = g * 8 + j;
      pk.u[j] = (k < HW) ? ydup[oo][HW - k] : (u16)0;
    }
    xfr_sw[b * 3584 + ((kb * 8 + at) * 4 + quad) * 16 + m] = pk.v;
  }

  // xfe: 8 rows x 8 shifts x 60 uint4
  uint4* xfe4 = (uint4*)xfe;
  for (int idx = t; idx < 8 * 8 * 60; idx += 512) {
    const int oo = idx / 480;
    const int rem = idx - oo * 480;
    const int S = rem / 60;
    const int g = rem - S * 60;
    const int c = og * 8 + oo;
    union { u16 u[8]; uint4 v; } pk;
#pragma unroll
    for (int j = 0; j < 8; ++j) pk.u[j] = ydup[oo][g * 8 + j + S];  // <= 493 < 588
    xfe4[((size_t)(b * NC + c) * 8 + S) * 60 + g] = pk.v;
  }
}

// ---- Stage 2: circular correlation via MFMA 16x16x32; conflict-free LDS A,
// B direct-from-global (L1-hot); in-reg 4:1 a-fold; bf16 W[b][a1][c*196+p] ----
// grid (8 b, 64 cpair); 256 threads = 4 waves.
__global__ __launch_bounds__(256, 2) void k_cooc(const uint4* __restrict__ xfr_sw,
                                                 const u16* __restrict__ xfe,
                                                 u32* __restrict__ W) {
  const int b     = blockIdx.x;
  const int cpair = blockIdx.y;
  const int t     = threadIdx.x;

  __shared__ __align__(16) uint4 Abuf[3584];   // 57344 B, frag order
  __shared__ __align__(16) u16 Obuf[32 * 200]; // 12800 B

  { // flat coalesced staging (xfr_sw is XCD-L2 resident)
    const uint4* src = xfr_sw + b * 3584;
    for (int j = t; j < 3584; j += 256) Abuf[j] = src[j];
  }
  __syncthreads();

  const int lane = t & 63;
  const int wv   = t >> 6;       // p-tiles {wv, wv+4, wv+8} (+12 for wave 0)
  const int n    = lane & 15;
  const int quad = lane >> 4;
  // per-lane B base: shift S=n&7 row, + (n&8) + quad*8; + p0 + kb*32 at use
  const u16* xbase = xfe + ((size_t)(b * NC) * 8) * CL + (n & 8) + quad * 8
                   + (size_t)(n & 7) * CL;

  for (int c2 = 0; c2 < 2; ++c2) {
    const int c = cpair * 2 + c2;
    const u16* xc = xbase + (size_t)c * (8 * CL);

    floatx4 acc[8][4];
#pragma unroll
    for (int at = 0; at < 8; ++at)
#pragma unroll
      for (int j = 0; j < 4; ++j) acc[at][j] = (floatx4){0.f, 0.f, 0.f, 0.f};

    for (int kb = 0; kb < 7; ++kb) {
      bf16x8 af[8];
#pragma unroll
      for (int at = 0; at < 8; ++at)   // lane-contiguous: base + lane*16B, no conflicts
        af[at] = *((const bf16x8*)&Abuf[(kb * 8 + at) * 64 + lane]);

#define DO_PT(JC)                                                                \
      {                                                                          \
        const int p0 = (wv + 4 * (JC)) * 16;                                     \
        const bf16x8 bv = *((const bf16x8*)&xc[p0 + kb * 32]);                   \
        _Pragma("unroll")                                                        \
        for (int at = 0; at < 8; ++at)                                           \
          acc[at][JC] = __builtin_amdgcn_mfma_f32_16x16x32_bf16(af[at], bv,      \
                                                                acc[at][JC], 0, 0, 0); \
      }
      DO_PT(0)
      DO_PT(1)
      DO_PT(2)
      if (wv == 0) { DO_PT(3) }
#undef DO_PT
    }

    // epilogue: in-register 4:1 a-fold, bf16 round, stage in Obuf[a1][p]
#define EPI(JC)                                                                  \
    {                                                                            \
      const int p = (wv + 4 * (JC)) * 16 + n;                                    \
      if (p < HW) {                                                              \
        _Pragma("unroll")                                                        \
        for (int a0t = 0; a0t < 2; ++a0t) {                                      \
          _Pragma("unroll")                                                      \
          for (int rr = 0; rr < 4; ++rr) {                                       \
            float v = fmaxf(fmaxf(acc[a0t][JC][rr], acc[a0t + 2][JC][rr]),       \
                            fmaxf(acc[a0t + 4][JC][rr], acc[a0t + 6][JC][rr]));  \
            const int a1 = a0t * 16 + quad * 4 + rr;                             \
            union { __hip_bfloat16 h; u16 u; } cv;                               \
            cv.h = __float2bfloat16(v);                                          \
            Obuf[a1 * 200 + p] = cv.u;                                           \
          }                                                                      \
        }                                                                        \
      }                                                                          \
    }
    EPI(0)
    EPI(1)
    EPI(2)
    if (wv == 0) { EPI(3) }
#undef EPI
    __syncthreads();

    { // coalesced store: 32 rows x 98 u32 into W[b][a1][c*98 + col]
      const u32* O32 = (const u32*)Obuf;
      u32* Wb = W + ((size_t)b * 32) * WROW + c * 98;
      for (int j = t; j < 32 * 98; j += 256) {
        const int row = (int)(((unsigned)j * 10700u) >> 20);   // j / 98
        const int col = j - row * 98;
        Wb[row * WROW + col] = O32[row * 100 + col];
      }
    }
    __syncthreads();
  }
}

// ---- Stage 3: per-slot max over 49 contributors (coalesced) + sqrt + batch sum ----
__global__ __launch_bounds__(256) void k_max(const u32* __restrict__ W,
                                             float* __restrict__ out,
                                             float* __restrict__ sums) {
  const int gid = blockIdx.x * 256 + threadIdx.x;   // 0..65535
  const int b  = gid >> 13;
  const int r0 = (gid & 8191) << 1;
  const u32* Wb = W + (size_t)b * 32 * WROW;

  float m0 = 0.f, m1 = 0.f;
#pragma unroll 4
  for (int a1 = 0; a1 < 32; ++a1) {
    const int s = (r0 - ((a1 * 8704) & 16383)) & 16383;   // even
    const u32 v = Wb[a1 * WROW + (s >> 1)];
    m0 = fmaxf(m0, __uint_as_float((v & 0xffffu) << 16));
    m1 = fmaxf(m1, __uint_as_float(v & 0xffff0000u));
    if (s < 8704) {   // second contributor s+16384 < 25088
      const u32 v2 = Wb[a1 * WROW + ((s + 16384) >> 1)];
      m0 = fmaxf(m0, __uint_as_float((v2 & 0xffffu) << 16));
      m1 = fmaxf(m1, __uint_as_float(v2 & 0xffff0000u));
    }
  }
  const int o = b * 16384 + r0;
  out[o]     = sqrtf(m0);
  out[o + 1] = sqrtf(m1);

  float s2 = m0 + m1;
#pragma unroll
  for (int off = 32; off > 0; off >>= 1) s2 += __shfl_down(s2, off, 64);
  __shared__ float part[4];
  if ((threadIdx.x & 63) == 0) part[threadIdx.x >> 6] = s2;
  __syncthreads();
  if (threadIdx.x == 0)
    atomicAdd(&sums[b], part[0] + part[1] + part[2] + part[3]);
}

// ---- Stage 4: normalize ----
__global__ __launch_bounds__(256) void k_norm(const float* __restrict__ sums,
                                              float* __restrict__ out) {
  const int gid = blockIdx.x * 256 + threadIdx.x;
  const int b = gid >> 14;
  out[gid] = out[gid] / (sums[b] + 1e-11f);
}

extern "C" void kernel_launch(void* const* d_in, const int* in_sizes, int n_in,
                              void* d_out, int out_size, void* d_ws, size_t ws_size,
                              hipStream_t stream) {
  const float* x  = (const float*)d_in[0];   // (8,512,16,16) fp32
  const float* wc = (const float*)d_in[1];   // (128,512) fp32

  char* ws = (char*)d_ws;
  uint4* xfr_sw = (uint4*)(ws + OFF_XFRSW);
  u16*   xfe    = (u16*)(ws + OFF_XFE);
  u32*   W      = (u32*)(ws + OFF_W);
  float* sums   = (float*)(ws + OFF_SUMS);

  hipMemsetAsync(sums, 0, NB * sizeof(float), stream);
  k_stage1<<<dim3(NB, 16), 512, 0, stream>>>(x, wc, xfr_sw, xfe);
  k_cooc<<<dim3(NB, 64), 256, 0, stream>>>(xfr_sw, xfe, W);
  k_max<<<256, 256, 0, stream>>>(W, (float*)d_out, sums);
  k_norm<<<(NB * 16384) / 256, 256, 0, stream>>>(sums, (float*)d_out);
}

// Round 5
// 126.451 us; speedup vs baseline: 1.0912x; 1.0912x over previous
//
#include <hip/hip_runtime.h>
#include <hip/hip_bf16.h>

typedef __bf16 bf16x8 __attribute__((ext_vector_type(8)));
typedef float floatx4 __attribute__((ext_vector_type(4)));
typedef unsigned short u16;
typedef unsigned int u32;

#define HW 196      // 14*14
#define NB 8
#define NC 128
#define CL 480      // xfe row stride (u16); reads bounded by 430 < 480
#define WROW 12544  // u32 per (b,a1) row of W (= 25088 bf16 = 128c * 196p)

// ws offsets (bytes)
#define OFF_XFRSW 0            // 8 * 3584 uint4 = 458752 B  (A in MFMA-frag order)
#define OFF_XFE   458752       // 8*128*8*480*2 = 7864320 B  (8 shift-copies / row)
#define OFF_W     8323072      // 12845056 B
#define OFF_SUMS  21168128

// ---- Stage 1: 1x1 conv + ReLU + 3x3 Gaussian blur; emits:
//  xfr_sw[b][kb7][at8][quad4][m16][j8]  = reversed row (A-operand, frag order)
//  xfe[b][c][S8][CL]                    = row_c[(m+S) mod 196] (B shift table)
// grid (8 b, 64 og-of-2-rows) = 512 blocks (2/CU, 16 waves/CU — R4 had 128 blocks
// = 0.5/CU and was latency-dead at 44 us). 512 threads = (K-half, pixel).
__global__ __launch_bounds__(512) void k_stage1(const float* __restrict__ x,
                                                const float* __restrict__ wc,
                                                uint4* __restrict__ xfr_sw,
                                                u16* __restrict__ xfe) {
  const int b   = blockIdx.x;
  const int og  = blockIdx.y;      // rows og*2, og*2+1
  const int t   = threadIdx.x;
  const int pix = t & 255;
  const int half = t >> 8;
  const float* xb = x + ((size_t)(b * 512 + half * 256)) * 256 + pix;
  const float* w0 = wc + og * 2 * 512 + half * 256;   // wave-uniform -> s_load

  float a0 = 0.f, a1 = 0.f;
#pragma unroll 8
  for (int i = 0; i < 256; ++i) {
    float xv = xb[(size_t)i * 256];
    a0 = fmaf(xv, w0[i], a0);
    a1 = fmaf(xv, w0[512 + i], a1);
  }

  __shared__ float ybuf[2][512];
  ybuf[0][t] = a0; ybuf[1][t] = a1;
  __syncthreads();
  if (t < 256) {
#pragma unroll
    for (int oo = 0; oo < 2; ++oo)
      ybuf[oo][t] = fmaxf(ybuf[oo][t] + ybuf[oo][256 + t], 0.f);
  }
  __syncthreads();

  const float GC = 0.63661977236758138f;   // gaussian var 0.25
  const float GE = GC * 0.13533528323661270f;
  const float GD = GC * 0.018315638888734179f;

  __shared__ u16 ydup[2][592];   // blurred row, bf16, replicated 3x (idx 0..587)
  if (t < HW) {
    const int h = t / 14, w2 = t - h * 14;
#pragma unroll
    for (int oo = 0; oo < 2; ++oo) {
      const float* yb = &ybuf[oo][h * 16 + w2];
      float v = GD * (yb[0] + yb[2] + yb[32] + yb[34])
              + GE * (yb[1] + yb[16] + yb[18] + yb[33])
              + GC * yb[17];
      union { __hip_bfloat16 h2; u16 u; } cv; cv.h2 = __float2bfloat16(v);
      ydup[oo][t] = cv.u; ydup[oo][t + 196] = cv.u; ydup[oo][t + 392] = cv.u;
    }
  }
  __syncthreads();

  // xfr_sw: per row 28 uint4 (g = k>>3), reversed: Arev[k] = y[(196-k)%196], 0 for k>=196
  if (t < 56) {
    const int oo = t / 28;
    const int g  = t - oo * 28;          // 0..27 = kb*4 + quad
    const int kb = g >> 2, quad = g & 3;
    const int c  = og * 2 + oo;
    const int at = c >> 4, m = c & 15;
    union { u16 u[8]; uint4 v; } pk;
#pragma unroll
    for (int j = 0; j < 8; ++j) {
      const int k = g * 8 + j;
      pk.u[j] = (k < HW) ? ydup[oo][HW - k] : (u16)0;
    }
    xfr_sw[b * 3584 + ((kb * 8 + at) * 4 + quad) * 16 + m] = pk.v;
  }

  // xfe: 2 rows x 8 shifts x 60 uint4
  uint4* xfe4 = (uint4*)xfe;
  for (int idx = t; idx < 2 * 8 * 60; idx += 512) {
    const int oo = idx / 480;
    const int rem = idx - oo * 480;
    const int S = rem / 60;
    const int g = rem - S * 60;
    const int c = og * 2 + oo;
    union { u16 u[8]; uint4 v; } pk;
#pragma unroll
    for (int j = 0; j < 8; ++j) pk.u[j] = ydup[oo][g * 8 + j + S];  // <= 486 < 588
    xfe4[((size_t)(b * NC + c) * 8 + S) * 60 + g] = pk.v;
  }
}

// ---- Stage 2: circular correlation via MFMA 16x16x32; conflict-free LDS A,
// B direct-from-global (L1-hot); in-reg 4:1 a-fold; bf16 W[b][a1][c*196+p] ----
// grid (8 b, 64 cpair); 256 threads = 4 waves.  (UNCHANGED from R4 on purpose —
// next round's top-5 will reveal its true cost now that stage1 shrinks.)
__global__ __launch_bounds__(256, 2) void k_cooc(const uint4* __restrict__ xfr_sw,
                                                 const u16* __restrict__ xfe,
                                                 u32* __restrict__ W) {
  const int b     = blockIdx.x;
  const int cpair = blockIdx.y;
  const int t     = threadIdx.x;

  __shared__ __align__(16) uint4 Abuf[3584];   // 57344 B, frag order
  __shared__ __align__(16) u16 Obuf[32 * 200]; // 12800 B

  { // flat coalesced staging (xfr_sw is XCD-L2 resident)
    const uint4* src = xfr_sw + b * 3584;
    for (int j = t; j < 3584; j += 256) Abuf[j] = src[j];
  }
  __syncthreads();

  const int lane = t & 63;
  const int wv   = t >> 6;       // p-tiles {wv, wv+4, wv+8} (+12 for wave 0)
  const int n    = lane & 15;
  const int quad = lane >> 4;
  // per-lane B base: shift S=n&7 row, + (n&8) + quad*8; + p0 + kb*32 at use
  const u16* xbase = xfe + ((size_t)(b * NC) * 8) * CL + (n & 8) + quad * 8
                   + (size_t)(n & 7) * CL;

  for (int c2 = 0; c2 < 2; ++c2) {
    const int c = cpair * 2 + c2;
    const u16* xc = xbase + (size_t)c * (8 * CL);

    floatx4 acc[8][4];
#pragma unroll
    for (int at = 0; at < 8; ++at)
#pragma unroll
      for (int j = 0; j < 4; ++j) acc[at][j] = (floatx4){0.f, 0.f, 0.f, 0.f};

    for (int kb = 0; kb < 7; ++kb) {
      bf16x8 af[8];
#pragma unroll
      for (int at = 0; at < 8; ++at)   // lane-contiguous: base + lane*16B, no conflicts
        af[at] = *((const bf16x8*)&Abuf[(kb * 8 + at) * 64 + lane]);

#define DO_PT(JC)                                                                \
      {                                                                          \
        const int p0 = (wv + 4 * (JC)) * 16;                                     \
        const bf16x8 bv = *((const bf16x8*)&xc[p0 + kb * 32]);                   \
        _Pragma("unroll")                                                        \
        for (int at = 0; at < 8; ++at)                                           \
          acc[at][JC] = __builtin_amdgcn_mfma_f32_16x16x32_bf16(af[at], bv,      \
                                                                acc[at][JC], 0, 0, 0); \
      }
      DO_PT(0)
      DO_PT(1)
      DO_PT(2)
      if (wv == 0) { DO_PT(3) }
#undef DO_PT
    }

    // epilogue: in-register 4:1 a-fold, bf16 round, stage in Obuf[a1][p]
#define EPI(JC)                                                                  \
    {                                                                            \
      const int p = (wv + 4 * (JC)) * 16 + n;                                    \
      if (p < HW) {                                                              \
        _Pragma("unroll")                                                        \
        for (int a0t = 0; a0t < 2; ++a0t) {                                      \
          _Pragma("unroll")                                                      \
          for (int rr = 0; rr < 4; ++rr) {                                       \
            float v = fmaxf(fmaxf(acc[a0t][JC][rr], acc[a0t + 2][JC][rr]),       \
                            fmaxf(acc[a0t + 4][JC][rr], acc[a0t + 6][JC][rr]));  \
            const int a1 = a0t * 16 + quad * 4 + rr;                             \
            union { __hip_bfloat16 h; u16 u; } cv;                               \
            cv.h = __float2bfloat16(v);                                          \
            Obuf[a1 * 200 + p] = cv.u;                                           \
          }                                                                      \
        }                                                                        \
      }                                                                          \
    }
    EPI(0)
    EPI(1)
    EPI(2)
    if (wv == 0) { EPI(3) }
#undef EPI
    __syncthreads();

    { // coalesced store: 32 rows x 98 u32 into W[b][a1][c*98 + col]
      const u32* O32 = (const u32*)Obuf;
      u32* Wb = W + ((size_t)b * 32) * WROW + c * 98;
      for (int j = t; j < 32 * 98; j += 256) {
        const int row = (int)(((unsigned)j * 10700u) >> 20);   // j / 98
        const int col = j - row * 98;
        Wb[row * WROW + col] = O32[row * 100 + col];
      }
    }
    __syncthreads();
  }
}

// ---- Stage 3: per-slot max over 49 contributors (coalesced) + sqrt + batch sum ----
__global__ __launch_bounds__(256) void k_max(const u32* __restrict__ W,
                                             float* __restrict__ out,
                                             float* __restrict__ sums) {
  const int gid = blockIdx.x * 256 + threadIdx.x;   // 0..65535
  const int b  = gid >> 13;
  const int r0 = (gid & 8191) << 1;
  const u32* Wb = W + (size_t)b * 32 * WROW;

  float m0 = 0.f, m1 = 0.f;
#pragma unroll 4
  for (int a1 = 0; a1 < 32; ++a1) {
    const int s = (r0 - ((a1 * 8704) & 16383)) & 16383;   // even
    const u32 v = Wb[a1 * WROW + (s >> 1)];
    m0 = fmaxf(m0, __uint_as_float((v & 0xffffu) << 16));
    m1 = fmaxf(m1, __uint_as_float(v & 0xffff0000u));
    if (s < 8704) {   // second contributor s+16384 < 25088
      const u32 v2 = Wb[a1 * WROW + ((s + 16384) >> 1)];
      m0 = fmaxf(m0, __uint_as_float((v2 & 0xffffu) << 16));
      m1 = fmaxf(m1, __uint_as_float(v2 & 0xffff0000u));
    }
  }
  const int o = b * 16384 + r0;
  out[o]     = sqrtf(m0);
  out[o + 1] = sqrtf(m1);

  float s2 = m0 + m1;
#pragma unroll
  for (int off = 32; off > 0; off >>= 1) s2 += __shfl_down(s2, off, 64);
  __shared__ float part[4];
  if ((threadIdx.x & 63) == 0) part[threadIdx.x >> 6] = s2;
  __syncthreads();
  if (threadIdx.x == 0)
    atomicAdd(&sums[b], part[0] + part[1] + part[2] + part[3]);
}

// ---- Stage 4: normalize ----
__global__ __launch_bounds__(256) void k_norm(const float* __restrict__ sums,
                                              float* __restrict__ out) {
  const int gid = blockIdx.x * 256 + threadIdx.x;
  const int b = gid >> 14;
  out[gid] = out[gid] / (sums[b] + 1e-11f);
}

extern "C" void kernel_launch(void* const* d_in, const int* in_sizes, int n_in,
                              void* d_out, int out_size, void* d_ws, size_t ws_size,
                              hipStream_t stream) {
  const float* x  = (const float*)d_in[0];   // (8,512,16,16) fp32
  const float* wc = (const float*)d_in[1];   // (128,512) fp32

  char* ws = (char*)d_ws;
  uint4* xfr_sw = (uint4*)(ws + OFF_XFRSW);
  u16*   xfe    = (u16*)(ws + OFF_XFE);
  u32*   W      = (u32*)(ws + OFF_W);
  float* sums   = (float*)(ws + OFF_SUMS);

  hipMemsetAsync(sums, 0, NB * sizeof(float), stream);
  k_stage1<<<dim3(NB, 64), 512, 0, stream>>>(x, wc, xfr_sw, xfe);
  k_cooc<<<dim3(NB, 64), 256, 0, stream>>>(xfr_sw, xfe, W);
  k_max<<<256, 256, 0, stream>>>(W, (float*)d_out, sums);
  k_norm<<<(NB * 16384) / 256, 256, 0, stream>>>(sums, (float*)d_out);
}

// Round 6
// 126.308 us; speedup vs baseline: 1.0925x; 1.0011x over previous
//
#include <hip/hip_runtime.h>
#include <hip/hip_bf16.h>

typedef __bf16 bf16x8 __attribute__((ext_vector_type(8)));
typedef float floatx4 __attribute__((ext_vector_type(4)));
typedef unsigned short u16;
typedef unsigned int u32;

#define HW 196      // 14*14
#define NB 8
#define NC 128
#define CL 480      // xfe row stride (u16); reads bounded by 487 < 588 source, 480 dest
#define WROW 12544  // u32 per (b,a1) row of W (= 25088 bf16 = 128c * 196p)

// ws offsets (bytes)
#define OFF_XFRSW 0            // 8 * 3584 uint4 = 458752 B  (A in MFMA-frag order)
#define OFF_XFE   458752       // 8*128*8*480*2 = 7864320 B  (8 shift-copies / row)
#define OFF_W     8323072      // 12845056 B
#define OFF_SUMS  21168128     // 32 B
#define OFF_YPART 21168160     // 8*8*8*16*256*4 = 8388608 B

// ---- Stage 1a: 1x1-conv GEMM, K-split fp32 partials ----
// grid (8 b, 8 og16, 8 ks64) = 512 blocks (2/CU). 512 thr = (K-half, pixel).
// R5 lesson: og-replicated full-K blocks re-read x[b] 64x from ONE XCD L2
// (134 MB/XCD -> ~30 us). K-split reads x exactly once: 4.2 MB/XCD.
__global__ __launch_bounds__(512) void k_conv(const float* __restrict__ x,
                                              const float* __restrict__ wc,
                                              float* __restrict__ Ypart) {
  const int b  = blockIdx.x;
  const int og = blockIdx.y;       // o rows og*16 .. +15
  const int ks = blockIdx.z;       // K range ks*64 .. +63
  const int t  = threadIdx.x;
  const int pix  = t & 255;
  const int half = t >> 8;         // wave-uniform (waves 0-3 / 4-7)

  const float* xb = x + ((size_t)(b * 512 + ks * 64 + half * 32)) * 256 + pix;
  const float* wp = wc + (og * 16) * 512 + ks * 64 + half * 32;   // s_load path

  float acc[16];
#pragma unroll
  for (int r = 0; r < 16; ++r) acc[r] = 0.f;
#pragma unroll 8
  for (int i = 0; i < 32; ++i) {
    float xv = xb[(size_t)i * 256];
#pragma unroll
    for (int r = 0; r < 16; ++r) acc[r] = fmaf(xv, wp[r * 512 + i], acc[r]);
  }

  __shared__ float red[16][512];
#pragma unroll
  for (int r = 0; r < 16; ++r) red[r][t] = acc[r];
  __syncthreads();

  if (t < 256) {
    float* yo = Ypart + (((size_t)(b * 8 + og) * 8 + ks) * 16) * 256 + t;
#pragma unroll
    for (int r = 0; r < 16; ++r)
      yo[r * 256] = red[r][t] + red[r][t + 256];
  }
}

// ---- Stage 1b: reduce ks-slices + ReLU + 3x3 Gaussian blur; emits:
//  xfr_sw[b][kb7][at8][quad4][m16][j8]  = reversed row (A-operand, frag order)
//  xfe[b][c][S8][CL]                    = row_c[(m+S) mod 196] (B shift table)
// grid (8 b, 32 rg-of-4-rows), 256 thr = pixel. XCD-local Ypart[b] reads.
__global__ __launch_bounds__(256) void k_reduce(const float* __restrict__ Ypart,
                                                uint4* __restrict__ xfr_sw,
                                                u16* __restrict__ xfe) {
  const int b  = blockIdx.x;
  const int rg = blockIdx.y;       // rows rg*4 .. +3
  const int t  = threadIdx.x;      // pixel

  __shared__ float ybuf[4][256];
  __shared__ u16 ydup[4][592];     // blurred row bf16, replicated 3x (idx 0..587)

#pragma unroll
  for (int oo = 0; oo < 4; ++oo) {
    const int o  = rg * 4 + oo;
    const int og = o >> 4, r = o & 15;
    const float* yp = Ypart + (((size_t)(b * 8 + og) * 8) * 16 + r) * 256 + t;
    float s = 0.f;
#pragma unroll
    for (int ks = 0; ks < 8; ++ks) s += yp[(size_t)ks * 16 * 256];
    ybuf[oo][t] = fmaxf(s, 0.f);
  }
  __syncthreads();

  const float GC = 0.63661977236758138f;   // gaussian var 0.25
  const float GE = GC * 0.13533528323661270f;
  const float GD = GC * 0.018315638888734179f;

  if (t < HW) {
    const int h = t / 14, w2 = t - h * 14;
#pragma unroll
    for (int oo = 0; oo < 4; ++oo) {
      const float* yb = &ybuf[oo][h * 16 + w2];
      float v = GD * (yb[0] + yb[2] + yb[32] + yb[34])
              + GE * (yb[1] + yb[16] + yb[18] + yb[33])
              + GC * yb[17];
      union { __hip_bfloat16 h2; u16 u; } cv; cv.h2 = __float2bfloat16(v);
      ydup[oo][t] = cv.u; ydup[oo][t + 196] = cv.u; ydup[oo][t + 392] = cv.u;
    }
  }
  __syncthreads();

  // xfr_sw: per row 28 uint4 (g = kb*4+quad), Arev[k] = y[(196-k)%196], 0 for k>=196
  if (t < 112) {
    const int oo = t / 28;
    const int g  = t - oo * 28;
    const int kb = g >> 2, quad = g & 3;
    const int c  = rg * 4 + oo;
    const int at = c >> 4, m = c & 15;
    union { u16 u[8]; uint4 v; } pk;
#pragma unroll
    for (int j = 0; j < 8; ++j) {
      const int k = g * 8 + j;
      pk.u[j] = (k < HW) ? ydup[oo][HW - k] : (u16)0;
    }
    xfr_sw[b * 3584 + ((kb * 8 + at) * 4 + quad) * 16 + m] = pk.v;
  }

  // xfe: 4 rows x 8 shifts x 60 uint4
  uint4* xfe4 = (uint4*)xfe;
  for (int idx = t; idx < 4 * 8 * 60; idx += 256) {
    const int oo = idx / 480;
    const int rem = idx - oo * 480;
    const int S = rem / 60;
    const int g = rem - S * 60;
    const int c = rg * 4 + oo;
    union { u16 u[8]; uint4 v; } pk;
#pragma unroll
    for (int j = 0; j < 8; ++j) pk.u[j] = ydup[oo][g * 8 + j + S];  // <= 487 < 588
    xfe4[((size_t)(b * NC + c) * 8 + S) * 60 + g] = pk.v;
  }
}

// ---- Stage 2: circular correlation via MFMA 16x16x32; conflict-free LDS A,
// B direct-from-global (L1/L2-hot); in-reg 4:1 a-fold; bf16 W[b][a1][c*196+p] ----
// grid (8 b, 64 cpair); 256 threads = 4 waves.  (unchanged — est ~4 us)
__global__ __launch_bounds__(256, 2) void k_cooc(const uint4* __restrict__ xfr_sw,
                                                 const u16* __restrict__ xfe,
                                                 u32* __restrict__ W) {
  const int b     = blockIdx.x;
  const int cpair = blockIdx.y;
  const int t     = threadIdx.x;

  __shared__ __align__(16) uint4 Abuf[3584];   // 57344 B, frag order
  __shared__ __align__(16) u16 Obuf[32 * 200]; // 12800 B

  { // flat coalesced staging (xfr_sw is XCD-L2 resident)
    const uint4* src = xfr_sw + b * 3584;
    for (int j = t; j < 3584; j += 256) Abuf[j] = src[j];
  }
  __syncthreads();

  const int lane = t & 63;
  const int wv   = t >> 6;       // p-tiles {wv, wv+4, wv+8} (+12 for wave 0)
  const int n    = lane & 15;
  const int quad = lane >> 4;
  const u16* xbase = xfe + ((size_t)(b * NC) * 8) * CL + (n & 8) + quad * 8
                   + (size_t)(n & 7) * CL;

  for (int c2 = 0; c2 < 2; ++c2) {
    const int c = cpair * 2 + c2;
    const u16* xc = xbase + (size_t)c * (8 * CL);

    floatx4 acc[8][4];
#pragma unroll
    for (int at = 0; at < 8; ++at)
#pragma unroll
      for (int j = 0; j < 4; ++j) acc[at][j] = (floatx4){0.f, 0.f, 0.f, 0.f};

    for (int kb = 0; kb < 7; ++kb) {
      bf16x8 af[8];
#pragma unroll
      for (int at = 0; at < 8; ++at)   // lane-contiguous: base + lane*16B, no conflicts
        af[at] = *((const bf16x8*)&Abuf[(kb * 8 + at) * 64 + lane]);

#define DO_PT(JC)                                                                \
      {                                                                          \
        const int p0 = (wv + 4 * (JC)) * 16;                                     \
        const bf16x8 bv = *((const bf16x8*)&xc[p0 + kb * 32]);                   \
        _Pragma("unroll")                                                        \
        for (int at = 0; at < 8; ++at)                                           \
          acc[at][JC] = __builtin_amdgcn_mfma_f32_16x16x32_bf16(af[at], bv,      \
                                                                acc[at][JC], 0, 0, 0); \
      }
      DO_PT(0)
      DO_PT(1)
      DO_PT(2)
      if (wv == 0) { DO_PT(3) }
#undef DO_PT
    }

#define EPI(JC)                                                                  \
    {                                                                            \
      const int p = (wv + 4 * (JC)) * 16 + n;                                    \
      if (p < HW) {                                                              \
        _Pragma("unroll")                                                        \
        for (int a0t = 0; a0t < 2; ++a0t) {                                      \
          _Pragma("unroll")                                                      \
          for (int rr = 0; rr < 4; ++rr) {                                       \
            float v = fmaxf(fmaxf(acc[a0t][JC][rr], acc[a0t + 2][JC][rr]),       \
                            fmaxf(acc[a0t + 4][JC][rr], acc[a0t + 6][JC][rr]));  \
            const int a1 = a0t * 16 + quad * 4 + rr;                             \
            union { __hip_bfloat16 h; u16 u; } cv;                               \
            cv.h = __float2bfloat16(v);                                          \
            Obuf[a1 * 200 + p] = cv.u;                                           \
          }                                                                      \
        }                                                                        \
      }                                                                          \
    }
    EPI(0)
    EPI(1)
    EPI(2)
    if (wv == 0) { EPI(3) }
#undef EPI
    __syncthreads();

    { // coalesced store: 32 rows x 98 u32 into W[b][a1][c*98 + col]
      const u32* O32 = (const u32*)Obuf;
      u32* Wb = W + ((size_t)b * 32) * WROW + c * 98;
      for (int j = t; j < 32 * 98; j += 256) {
        const int row = (int)(((unsigned)j * 10700u) >> 20);   // j / 98
        const int col = j - row * 98;
        Wb[row * WROW + col] = O32[row * 100 + col];
      }
    }
    __syncthreads();
  }
}

// ---- Stage 3: per-slot max over 49 contributors (coalesced) + sqrt + batch sum ----
__global__ __launch_bounds__(256) void k_max(const u32* __restrict__ W,
                                             float* __restrict__ out,
                                             float* __restrict__ sums) {
  const int gid = blockIdx.x * 256 + threadIdx.x;   // 0..65535
  const int b  = gid >> 13;
  const int r0 = (gid & 8191) << 1;
  const u32* Wb = W + (size_t)b * 32 * WROW;

  float m0 = 0.f, m1 = 0.f;
#pragma unroll 4
  for (int a1 = 0; a1 < 32; ++a1) {
    const int s = (r0 - ((a1 * 8704) & 16383)) & 16383;   // even
    const u32 v = Wb[a1 * WROW + (s >> 1)];
    m0 = fmaxf(m0, __uint_as_float((v & 0xffffu) << 16));
    m1 = fmaxf(m1, __uint_as_float(v & 0xffff0000u));
    if (s < 8704) {   // second contributor s+16384 < 25088
      const u32 v2 = Wb[a1 * WROW + ((s + 16384) >> 1)];
      m0 = fmaxf(m0, __uint_as_float((v2 & 0xffffu) << 16));
      m1 = fmaxf(m1, __uint_as_float(v2 & 0xffff0000u));
    }
  }
  const int o = b * 16384 + r0;
  out[o]     = sqrtf(m0);
  out[o + 1] = sqrtf(m1);

  float s2 = m0 + m1;
#pragma unroll
  for (int off = 32; off > 0; off >>= 1) s2 += __shfl_down(s2, off, 64);
  __shared__ float part[4];
  if ((threadIdx.x & 63) == 0) part[threadIdx.x >> 6] = s2;
  __syncthreads();
  if (threadIdx.x == 0)
    atomicAdd(&sums[b], part[0] + part[1] + part[2] + part[3]);
}

// ---- Stage 4: normalize ----
__global__ __launch_bounds__(256) void k_norm(const float* __restrict__ sums,
                                              float* __restrict__ out) {
  const int gid = blockIdx.x * 256 + threadIdx.x;
  const int b = gid >> 14;
  out[gid] = out[gid] / (sums[b] + 1e-11f);
}

extern "C" void kernel_launch(void* const* d_in, const int* in_sizes, int n_in,
                              void* d_out, int out_size, void* d_ws, size_t ws_size,
                              hipStream_t stream) {
  const float* x  = (const float*)d_in[0];   // (8,512,16,16) fp32
  const float* wc = (const float*)d_in[1];   // (128,512) fp32

  char* ws = (char*)d_ws;
  uint4* xfr_sw = (uint4*)(ws + OFF_XFRSW);
  u16*   xfe    = (u16*)(ws + OFF_XFE);
  u32*   W      = (u32*)(ws + OFF_W);
  float* sums   = (float*)(ws + OFF_SUMS);
  float* Ypart  = (float*)(ws + OFF_YPART);

  hipMemsetAsync(sums, 0, NB * sizeof(float), stream);
  k_conv<<<dim3(NB, 8, 8), 512, 0, stream>>>(x, wc, Ypart);
  k_reduce<<<dim3(NB, 32), 256, 0, stream>>>(Ypart, xfr_sw, xfe);
  k_cooc<<<dim3(NB, 64), 256, 0, stream>>>(xfr_sw, xfe, W);
  k_max<<<256, 256, 0, stream>>>(W, (float*)d_out, sums);
  k_norm<<<(NB * 16384) / 256, 256, 0, stream>>>(sums, (float*)d_out);
}